// Round 8
// baseline (782.655 us; speedup 1.0000x reference)
//
#include <hip/hip_runtime.h>
#include <hip/hip_bf16.h>
#include <cstdint>

// Problem constants
#define BB  8
#define CH  64
#define TT  4096
#define KNN 9
#define NEG_INF (-3.402823466e38f)
#define SLOTS 48          // candidate bucket per row (both halves)
#define KTH   12          // θ = 12th largest of per-half lane-union

typedef short  s16x8 __attribute__((ext_vector_type(8)));   // 8 bf16 MFMA frag
typedef float  f32x4 __attribute__((ext_vector_type(4)));   // MFMA acc

// Workspace layout (float units) — end 16,060,416 floats = 64.2 MB
constexpr size_t OFF_UB  = 0;                                  // u bf16 [B][9][T][C] ushort
constexpr size_t OFF_QTF = (size_t)BB*KNN*TT*CH/2;             //  9,437,184 qhatT f32 [B][T][C]
constexpr size_t OFF_KTF = OFF_QTF + (size_t)BB*TT*CH;         // 11,534,336 khatT f32
constexpr size_t OFF_QTB = OFF_KTF + (size_t)BB*TT*CH;         // 13,631,488 qhatT bf16 ushort
constexpr size_t OFF_KTB = OFF_QTB + (size_t)BB*TT*CH/2;       // 14,680,064 khatT bf16
constexpr size_t OFF_IDX = OFF_KTB + (size_t)BB*TT*CH/2;       // 15,728,640 idx [B][T][9]
constexpr size_t OFF_CWP = OFF_IDX + (size_t)BB*TT*KNN;        // 16,023,552 cwp [9][64][64]

__device__ __forceinline__ unsigned short f2bf(float f) {
    unsigned u = __float_as_uint(f);
    return (unsigned short)((u + 0x7FFFu + ((u >> 16) & 1u)) >> 16);
}

// value-only ascending top-4 (3 med3 + 1 max); reference params keep SROA.
__device__ __forceinline__ void insert4(float w, float (&s)[4]) {
    s[0] = __builtin_amdgcn_fmed3f(s[0], s[1], w);
    s[1] = __builtin_amdgcn_fmed3f(s[1], s[2], w);
    s[2] = __builtin_amdgcn_fmed3f(s[2], s[3], w);
    s[3] = fmaxf(s[3], w);
}

// θ = KTH-th largest of the union of the quad's 16 top-4 lists (destroys
// lists). Union ⊆ half-row ⇒ θ ≤ half-row's KTH-th largest (safe threshold).
__device__ __forceinline__ float popTheta4(float (&s)[4], int lane) {
    float theta = NEG_INF;
    #pragma unroll 1
    for (int p = 0; p < KTH; ++p) {
        float h = s[3];
        float m = h;
        m = fmaxf(m, __shfl_xor(m, 1));
        m = fmaxf(m, __shfl_xor(m, 2));
        m = fmaxf(m, __shfl_xor(m, 4));
        m = fmaxf(m, __shfl_xor(m, 8));
        unsigned long long bal = __ballot(h == m);
        unsigned qb = (unsigned)((bal >> (lane & 48)) & 0xFFFFull);
        int owner = __ffs(qb) - 1;
        if ((lane & 15) == owner) {
            s[3] = s[2]; s[2] = s[1]; s[1] = s[0]; s[0] = NEG_INF;
        }
        theta = m;
    }
    return theta;
}

// exact sorted-9 insert, value desc w/ index-asc tiebreak (final sort only)
__device__ __forceinline__ void insert9x(float w, int wi, float (&s)[9], int (&si)[9]) {
    bool c[9];
    #pragma unroll
    for (int k = 0; k < 9; ++k) c[k] = (w > s[k]) || (w == s[k] && wi < si[k]);
    #pragma unroll
    for (int k = 0; k < 8; ++k) si[k] = c[k + 1] ? si[k + 1] : (c[k] ? wi : si[k]);
    si[8] = c[8] ? wi : si[8];
    #pragma unroll
    for (int k = 0; k < 8; ++k) s[k] = c[k + 1] ? s[k + 1] : (c[k] ? w : s[k]);
    s[8] = c[8] ? w : s[8];
}

// ---------------------------------------------------------------------------
// K0: repack conv_w[o][cc*9+kk] -> cwp[kk][cc][o]
// ---------------------------------------------------------------------------
__global__ void repack_cw_kernel(const float* __restrict__ cw, float* __restrict__ cwp) {
    int e = blockIdx.x * blockDim.x + threadIdx.x;
    if (e >= KNN * CH * CH) return;
    int o  = e & 63;
    int cc = (e >> 6) & 63;
    int kk = e >> 12;
    cwp[e] = cw[o * (CH * KNN) + cc * KNN + kk];
}

// ---------------------------------------------------------------------------
// K1: QKV + L2 normalize + u-projection (u bf16) + q/k T-layout fp32 & bf16
// ---------------------------------------------------------------------------
__global__ __launch_bounds__(256) void qkvu_kernel(
        const float* __restrict__ x,
        const float* __restrict__ Wq, const float* __restrict__ Wk, const float* __restrict__ Wv,
        const float* __restrict__ cwp,
        float* __restrict__ qtf, float* __restrict__ ktf,
        unsigned short* __restrict__ qtb, unsigned short* __restrict__ ktb,
        unsigned short* __restrict__ ub) {
    __shared__ __align__(16) float xs[CH * 64];
    __shared__ __align__(16) float vs[CH * 64];
    __shared__ __align__(16) float wl[CH * 64];
    __shared__ float pq[4 * 64], pk[4 * 64];

    const int b   = blockIdx.x >> 6;
    const int tb  = blockIdx.x & 63;
    const int tid = threadIdx.x;

    const float* xb = x + ((size_t)b * CH) * TT + tb * 64;
    #pragma unroll
    for (int m = 0; m < 16; ++m) {
        int l = tid + 256 * m;
        xs[l] = xb[(size_t)(l >> 6) * TT + (l & 63)];
    }
    __syncthreads();

    const int t = tid & 63;
    const int g = __builtin_amdgcn_readfirstlane(tid >> 6);
    const int d0 = g * 16;

    float qa[16], ka[16], va[16];
    #pragma unroll
    for (int dd = 0; dd < 16; ++dd) { qa[dd] = 0.f; ka[dd] = 0.f; va[dd] = 0.f; }

    #pragma unroll 4
    for (int c = 0; c < CH; ++c) {
        float xv = xs[c * 64 + t];
        #pragma unroll
        for (int dd = 0; dd < 16; ++dd) {
            qa[dd] = fmaf(Wq[(d0 + dd) * CH + c], xv, qa[dd]);
            ka[dd] = fmaf(Wk[(d0 + dd) * CH + c], xv, ka[dd]);
            va[dd] = fmaf(Wv[(d0 + dd) * CH + c], xv, va[dd]);
        }
    }

    float sq = 0.f, sk = 0.f;
    #pragma unroll
    for (int dd = 0; dd < 16; ++dd) { sq = fmaf(qa[dd], qa[dd], sq); sk = fmaf(ka[dd], ka[dd], sk); }
    pq[g * 64 + t] = sq;
    pk[g * 64 + t] = sk;
    __syncthreads();

    const float nq = sqrtf(pq[t] + pq[64 + t] + pq[128 + t] + pq[192 + t]);
    const float nk = sqrtf(pk[t] + pk[64 + t] + pk[128 + t] + pk[192 + t]);
    const float isq = 1.0f / fmaxf(nq, 1e-12f);
    const float isk = 1.0f / fmaxf(nk, 1e-12f);

    const size_t tg = (size_t)tb * 64 + t;
    float qn[16], kn[16];
    #pragma unroll
    for (int dd = 0; dd < 16; ++dd) {
        qn[dd] = qa[dd] * isq;
        kn[dd] = ka[dd] * isk;
        vs[(d0 + dd) * 64 + t] = va[dd];
    }
    float* qf = qtf + ((size_t)b * TT + tg) * CH + d0;
    float* kf = ktf + ((size_t)b * TT + tg) * CH + d0;
    #pragma unroll
    for (int p = 0; p < 4; ++p) {
        *(float4*)&qf[p * 4] = make_float4(qn[p*4], qn[p*4+1], qn[p*4+2], qn[p*4+3]);
        *(float4*)&kf[p * 4] = make_float4(kn[p*4], kn[p*4+1], kn[p*4+2], kn[p*4+3]);
    }
    unsigned* qh = (unsigned*)(qtb + ((size_t)b * TT + tg) * CH + d0);
    unsigned* kh = (unsigned*)(ktb + ((size_t)b * TT + tg) * CH + d0);
    #pragma unroll
    for (int p = 0; p < 8; ++p) {
        qh[p] = (unsigned)f2bf(qn[2*p]) | ((unsigned)f2bf(qn[2*p+1]) << 16);
        kh[p] = (unsigned)f2bf(kn[2*p]) | ((unsigned)f2bf(kn[2*p+1]) << 16);
    }
    __syncthreads();

    const int to = tid & 15;
    const int tt = tid >> 4;
    for (int kk = 0; kk < KNN; ++kk) {
        #pragma unroll
        for (int m = 0; m < 16; ++m) {
            int l = tid + 256 * m;
            wl[l] = cwp[kk * (CH * CH) + l];
        }
        __syncthreads();
        float acc[4][4];
        #pragma unroll
        for (int i = 0; i < 4; ++i)
            #pragma unroll
            for (int j = 0; j < 4; ++j) acc[i][j] = 0.f;

        #pragma unroll 8
        for (int cc = 0; cc < CH; ++cc) {
            float4 wv = *(const float4*)&wl[cc * 64 + 4 * to];
            float4 vv = *(const float4*)&vs[cc * 64 + 4 * tt];
            const float wj[4] = {wv.x, wv.y, wv.z, wv.w};
            const float vi[4] = {vv.x, vv.y, vv.z, vv.w};
            #pragma unroll
            for (int i = 0; i < 4; ++i)
                #pragma unroll
                for (int j = 0; j < 4; ++j) acc[i][j] = fmaf(vi[i], wj[j], acc[i][j]);
        }
        #pragma unroll
        for (int i = 0; i < 4; ++i) {
            size_t row = (size_t)(b * KNN + kk) * TT + tb * 64 + 4 * tt + i;
            unsigned w0 = (unsigned)f2bf(acc[i][0]) | ((unsigned)f2bf(acc[i][1]) << 16);
            unsigned w1 = (unsigned)f2bf(acc[i][2]) | ((unsigned)f2bf(acc[i][3]) << 16);
            *(uint2*)&ub[row * CH + 4 * to] = make_uint2(w0, w1);
        }
        __syncthreads();
    }
}

// ---------------------------------------------------------------------------
// DIAGNOSTIC (round 8): loads + MFMA ONLY, r0's exact addressing/schedule.
// 8 reps = 4x the real kernel's two passes => readout = dur/4 vs sim's 180 µs.
// No insert/θ/collect/LDS/atomics. Results kept live via float fold written
// to scratch (idx region, overwritten by the real sim_topk afterwards).
// Lane rotation (l15+rep)&15 makes addresses rep-dependent => no LICM/CSE
// of the repeated passes. Runs AFTER qkvu (needs qtb/ktb).
// ---------------------------------------------------------------------------
__global__ __launch_bounds__(256, 2) void abl_ldmfma_kernel(
        const unsigned short* __restrict__ qtb, const unsigned short* __restrict__ ktb,
        float* __restrict__ scratch) {
    const int b    = blockIdx.x & 7;
    const int ib   = blockIdx.x >> 3;
    const int tid  = threadIdx.x;
    const int lane = tid & 63;
    const int w    = tid >> 6;
    const int w2r  = w >> 1;
    const int w2c  = w & 1;
    const int quad = lane >> 4;
    const int l15  = lane & 15;

    const unsigned short* kb = ktb + ((size_t)b * TT + ib * 64 + w2r * 32) * CH;
    s16x8 ka[2][2];
    #pragma unroll
    for (int rt = 0; rt < 2; ++rt)
        #pragma unroll
        for (int ks = 0; ks < 2; ++ks)
            ka[rt][ks] = *(const s16x8*)(kb + (size_t)(rt * 16 + l15) * CH + ks * 32 + quad * 8);

    const unsigned short* qbB = qtb + ((size_t)b * TT + w2c * 2048) * CH;

    float s = 0.f;
    #pragma unroll 1
    for (int rep = 0; rep < 8; ++rep) {
        const int lr = (l15 + rep) & 15;     // rep-dependent addressing: no hoist
        #pragma unroll 1
        for (int jt = 0; jt < 16; ++jt) {
            const unsigned short* qrow = qbB + (size_t)(jt * 128 + lr) * CH + quad * 8;
            s16x8 qf[8][2];
            #pragma unroll
            for (int jj = 0; jj < 8; ++jj)
                #pragma unroll
                for (int ks = 0; ks < 2; ++ks)
                    qf[jj][ks] = *(const s16x8*)(qrow + (size_t)jj * 16 * CH + ks * 32);

            f32x4 acc[2][8];
            #pragma unroll
            for (int rt = 0; rt < 2; ++rt)
                #pragma unroll
                for (int jj = 0; jj < 8; ++jj) acc[rt][jj] = (f32x4){0.f, 0.f, 0.f, 0.f};
            #pragma unroll
            for (int ks = 0; ks < 2; ++ks)
                #pragma unroll
                for (int rt = 0; rt < 2; ++rt)
                    #pragma unroll
                    for (int jj = 0; jj < 8; ++jj)
                        acc[rt][jj] = __builtin_amdgcn_mfma_f32_16x16x32_bf16(ka[rt][ks], qf[jj][ks], acc[rt][jj], 0, 0, 0);

            #pragma unroll
            for (int rt = 0; rt < 2; ++rt)
                #pragma unroll
                for (int jj = 0; jj < 8; ++jj)
                    s += acc[rt][jj][0] + acc[rt][jj][1] + acc[rt][jj][2] + acc[rt][jj][3];
        }
    }
    scratch[(size_t)blockIdx.x * 256 + tid] = s;
}

// ---------------------------------------------------------------------------
// K2: BARRIER-FREE bf16-MFMA sim + top-4 prefilter + θ-collect + exact rescore
//     (r0 baseline — best measured: 180 µs, total 334 µs)
// ---------------------------------------------------------------------------
__global__ __launch_bounds__(256, 2) void sim_topk_kernel(
        const unsigned short* __restrict__ qtb, const unsigned short* __restrict__ ktb,
        const float* __restrict__ qtf, const float* __restrict__ ktf,
        int* __restrict__ idxout) {
    __shared__ int   cnt[64];
    __shared__ int   bkt[64 * SLOTS];
    __shared__ float wbf[64 * SLOTS];

    const int b    = blockIdx.x & 7;
    const int ib   = blockIdx.x >> 3;      // 0..63
    const int tid  = threadIdx.x;
    const int lane = tid & 63;
    const int w    = tid >> 6;             // wave 0..3
    const int w2r  = w >> 1;               // row half
    const int w2c  = w & 1;                // col half
    const int quad = lane >> 4;
    const int l15  = lane & 15;

    if (tid < 64) cnt[tid] = 0;
    __syncthreads();

    // k A-fragments in registers: rows w2r*32 + rt*16 + l15, k = quad*8+ks*32
    const unsigned short* kb = ktb + ((size_t)b * TT + ib * 64 + w2r * 32) * CH;
    s16x8 ka[2][2];
    #pragma unroll
    for (int rt = 0; rt < 2; ++rt)
        #pragma unroll
        for (int ks = 0; ks < 2; ++ks)
            ka[rt][ks] = *(const s16x8*)(kb + (size_t)(rt * 16 + l15) * CH + ks * 32 + quad * 8);

    const unsigned short* qbB = qtb + ((size_t)b * TT + w2c * 2048) * CH;

    float s[2][4][4];
    #pragma unroll
    for (int rt = 0; rt < 2; ++rt)
        #pragma unroll
        for (int rg = 0; rg < 4; ++rg)
            #pragma unroll
            for (int k = 0; k < 4; ++k) s[rt][rg][k] = NEG_INF;

    // ------------------ PASS A: values-only top-4 (no barriers) ------------
    for (int jt = 0; jt < 16; ++jt) {
        const unsigned short* qrow = qbB + (size_t)(jt * 128 + l15) * CH + quad * 8;
        s16x8 qf[8][2];
        #pragma unroll
        for (int jj = 0; jj < 8; ++jj)
            #pragma unroll
            for (int ks = 0; ks < 2; ++ks)
                qf[jj][ks] = *(const s16x8*)(qrow + (size_t)jj * 16 * CH + ks * 32);

        f32x4 acc[2][8];
        #pragma unroll
        for (int rt = 0; rt < 2; ++rt)
            #pragma unroll
            for (int jj = 0; jj < 8; ++jj) acc[rt][jj] = (f32x4){0.f, 0.f, 0.f, 0.f};
        #pragma unroll
        for (int ks = 0; ks < 2; ++ks)
            #pragma unroll
            for (int rt = 0; rt < 2; ++rt)
                #pragma unroll
                for (int jj = 0; jj < 8; ++jj)
                    acc[rt][jj] = __builtin_amdgcn_mfma_f32_16x16x32_bf16(ka[rt][ks], qf[jj][ks], acc[rt][jj], 0, 0, 0);

        #pragma unroll
        for (int rt = 0; rt < 2; ++rt)
            #pragma unroll
            for (int jj = 0; jj < 8; ++jj) {
                insert4(acc[rt][jj][0], s[rt][0]);
                insert4(acc[rt][jj][1], s[rt][1]);
                insert4(acc[rt][jj][2], s[rt][2]);
                insert4(acc[rt][jj][3], s[rt][3]);
            }
    }

    // per-(row,half) θ — valid per half; no cross-wave merge needed
    float th[2][4];
    #pragma unroll
    for (int rt = 0; rt < 2; ++rt) {
        th[rt][0] = popTheta4(s[rt][0], lane);
        th[rt][1] = popTheta4(s[rt][1], lane);
        th[rt][2] = popTheta4(s[rt][2], lane);
        th[rt][3] = popTheta4(s[rt][3], lane);
    }

    // ------------------ PASS B: recompute (bitwise-identical) + collect ----
    for (int jt = 0; jt < 16; ++jt) {
        const unsigned short* qrow = qbB + (size_t)(jt * 128 + l15) * CH + quad * 8;
        s16x8 qf[8][2];
        #pragma unroll
        for (int jj = 0; jj < 8; ++jj)
            #pragma unroll
            for (int ks = 0; ks < 2; ++ks)
                qf[jj][ks] = *(const s16x8*)(qrow + (size_t)jj * 16 * CH + ks * 32);

        f32x4 acc[2][8];
        #pragma unroll
        for (int rt = 0; rt < 2; ++rt)
            #pragma unroll
            for (int jj = 0; jj < 8; ++jj) acc[rt][jj] = (f32x4){0.f, 0.f, 0.f, 0.f};
        #pragma unroll
        for (int ks = 0; ks < 2; ++ks)
            #pragma unroll
            for (int rt = 0; rt < 2; ++rt)
                #pragma unroll
                for (int jj = 0; jj < 8; ++jj)
                    acc[rt][jj] = __builtin_amdgcn_mfma_f32_16x16x32_bf16(ka[rt][ks], qf[jj][ks], acc[rt][jj], 0, 0, 0);

        #pragma unroll
        for (int rt = 0; rt < 2; ++rt)
            #pragma unroll
            for (int jj = 0; jj < 8; ++jj) {
                const int j = w2c * 2048 + jt * 128 + jj * 16 + l15;
                #pragma unroll
                for (int rg = 0; rg < 4; ++rg) {
                    if (acc[rt][jj][rg] >= th[rt][rg]) {
                        int rowl = w2r * 32 + rt * 16 + quad * 4 + rg;
                        int sl = atomicAdd(&cnt[rowl], 1);
                        if (sl < SLOTS) bkt[rowl * SLOTS + sl] = j;
                    }
                }
            }
    }
    __syncthreads();

    // ------------------ exact fp32 rescore (L2-hot q/k fp32) ---------------
    {
        int r = tid >> 2, sub = tid & 3;
        int n = min(cnt[r], SLOTS);
        const float* krow = ktf + ((size_t)b * TT + ib * 64 + r) * CH;
        for (int m = sub; m < n; m += 4) {
            int j = bkt[r * SLOTS + m];
            const float* qrow = qtf + ((size_t)b * TT + j) * CH;
            float wv = 0.f;
            #pragma unroll
            for (int c4 = 0; c4 < 16; ++c4) {
                float4 kv = *(const float4*)&krow[c4 * 4];
                float4 qv = *(const float4*)&qrow[c4 * 4];
                wv = fmaf(kv.x, qv.x, wv); wv = fmaf(kv.y, qv.y, wv);
                wv = fmaf(kv.z, qv.z, wv); wv = fmaf(kv.w, qv.w, wv);
            }
            wbf[r * SLOTS + m] = wv;
        }
    }
    __syncthreads();

    if (tid < 64) {
        int n = min(cnt[tid], SLOTS);
        float s9[9]; int si9[9];
        #pragma unroll
        for (int k = 0; k < 9; ++k) { s9[k] = NEG_INF; si9[k] = 0x7fffffff; }
        #pragma unroll 1
        for (int m = 0; m < n; ++m) insert9x(wbf[tid * SLOTS + m], bkt[tid * SLOTS + m], s9, si9);
        int* orow = idxout + ((size_t)b * TT + ib * 64 + tid) * KNN;
        #pragma unroll
        for (int m = 0; m < 9; ++m) orow[m] = si9[8 - m];
    }
}

// ---------------------------------------------------------------------------
// K3: out[b][o][t] = conv_b[o] + sum_kk u_bf16[b][kk][idx[t][kk]][o]
// ---------------------------------------------------------------------------
__global__ __launch_bounds__(256) void gather_conv_kernel(
        const unsigned short* __restrict__ ub, const int* __restrict__ idxin,
        const float* __restrict__ conv_b, float* __restrict__ out) {
    __shared__ int   sidx[64 * KNN];
    __shared__ float cb[CH];
    const int b   = blockIdx.x & 7;
    const int tb  = blockIdx.x >> 3;
    const int tid = threadIdx.x;

    if (tid < CH) cb[tid] = conv_b[tid];
    const int* ig = idxin + ((size_t)b * TT + tb * 64) * KNN;
    for (int l = tid; l < 64 * KNN; l += 256) sidx[l] = ig[l];
    __syncthreads();

    const int tl = tid & 63;
    const int og = tid >> 6;
    const int o0 = og * 16;

    float acc[16];
    #pragma unroll
    for (int q = 0; q < 16; ++q) acc[q] = cb[o0 + q];

    #pragma unroll
    for (int kk = 0; kk < KNN; ++kk) {
        int j = sidx[tl * KNN + kk];
        const unsigned short* up = ub + (((size_t)(b * KNN + kk)) * TT + j) * CH + o0;
        #pragma unroll
        for (int q8 = 0; q8 < 2; ++q8) {
            uint4 raw = *(const uint4*)&up[q8 * 8];
            unsigned rw[4] = {raw.x, raw.y, raw.z, raw.w};
            #pragma unroll
            for (int p = 0; p < 4; ++p) {
                acc[q8 * 8 + 2 * p]     += __uint_as_float(rw[p] << 16);
                acc[q8 * 8 + 2 * p + 1] += __uint_as_float(rw[p] & 0xFFFF0000u);
            }
        }
    }
    const int t = tb * 64 + tl;
    #pragma unroll
    for (int q = 0; q < 16; ++q)
        out[((size_t)b * CH + o0 + q) * TT + t] = acc[q];
}

// ---------------------------------------------------------------------------
extern "C" void kernel_launch(void* const* d_in, const int* in_sizes, int n_in,
                              void* d_out, int out_size, void* d_ws, size_t ws_size,
                              hipStream_t stream) {
    const float* x   = (const float*)d_in[0];
    const float* Wq  = (const float*)d_in[1];
    const float* Wk  = (const float*)d_in[2];
    const float* Wv  = (const float*)d_in[3];
    const float* cw  = (const float*)d_in[4];
    const float* cbp = (const float*)d_in[5];

    float* ws = (float*)d_ws;
    unsigned short* ub  = (unsigned short*)(ws + OFF_UB);
    float* qtf          = ws + OFF_QTF;
    float* ktf          = ws + OFF_KTF;
    unsigned short* qtb = (unsigned short*)(ws + OFF_QTB);
    unsigned short* ktb = (unsigned short*)(ws + OFF_KTB);
    int*   idx          = (int*)(ws + OFF_IDX);
    float* cwp          = ws + OFF_CWP;
    float* out          = (float*)d_out;

    repack_cw_kernel<<<(KNN * CH * CH + 255) / 256, 256, 0, stream>>>(cw, cwp);
    qkvu_kernel<<<BB * 64, 256, 0, stream>>>(x, Wq, Wk, Wv, cwp, qtf, ktf, qtb, ktb, ub);
    // diagnostic probe: writes into idx region, fully overwritten by sim_topk
    abl_ldmfma_kernel<<<BB * 64, 256, 0, stream>>>(qtb, ktb, (float*)idx);
    sim_topk_kernel<<<BB * 64, 256, 0, stream>>>(qtb, ktb, qtf, ktf, idx);
    gather_conv_kernel<<<BB * 64, 256, 0, stream>>>(ub, idx, cbp, out);
}

// Round 9
// 296.552 us; speedup vs baseline: 2.6392x; 2.6392x over previous
//
#include <hip/hip_runtime.h>
#include <hip/hip_bf16.h>
#include <cstdint>

// Problem constants
#define BB  8
#define CH  64
#define TT  4096
#define KNN 9
#define NEG_INF (-3.402823466e38f)
#define SLOTS 48          // candidate bucket per row (both halves)
#define KTH   12          // θ = 12th largest of per-half lane-union

typedef short  s16x8 __attribute__((ext_vector_type(8)));   // 8 bf16 MFMA frag
typedef float  f32x4 __attribute__((ext_vector_type(4)));   // MFMA acc

// Workspace layout (float units) — end 16,060,416 floats = 64.2 MB
constexpr size_t OFF_UB  = 0;                                  // u bf16 [B][9][T][C] ushort
constexpr size_t OFF_QTF = (size_t)BB*KNN*TT*CH/2;             //  9,437,184 qhatT f32 [B][T][C]
constexpr size_t OFF_KTF = OFF_QTF + (size_t)BB*TT*CH;         // 11,534,336 khatT f32
constexpr size_t OFF_QTB = OFF_KTF + (size_t)BB*TT*CH;         // 13,631,488 q bf16 FRAGMENT order
constexpr size_t OFF_KTB = OFF_QTB + (size_t)BB*TT*CH/2;       // 14,680,064 khatT bf16 row-major
constexpr size_t OFF_IDX = OFF_KTB + (size_t)BB*TT*CH/2;       // 15,728,640 idx [B][T][9]
constexpr size_t OFF_CWP = OFF_IDX + (size_t)BB*TT*KNN;        // 16,023,552 cwp [9][64][64]

__device__ __forceinline__ unsigned short f2bf(float f) {
    unsigned u = __float_as_uint(f);
    return (unsigned short)((u + 0x7FFFu + ((u >> 16) & 1u)) >> 16);
}

// value-only ascending top-4 (3 med3 + 1 max); reference params keep SROA.
__device__ __forceinline__ void insert4(float w, float (&s)[4]) {
    s[0] = __builtin_amdgcn_fmed3f(s[0], s[1], w);
    s[1] = __builtin_amdgcn_fmed3f(s[1], s[2], w);
    s[2] = __builtin_amdgcn_fmed3f(s[2], s[3], w);
    s[3] = fmaxf(s[3], w);
}

// θ = KTH-th largest of the union of the quad's 16 top-4 lists (destroys
// lists). Union ⊆ half-row ⇒ θ ≤ half-row's KTH-th largest (safe threshold).
__device__ __forceinline__ float popTheta4(float (&s)[4], int lane) {
    float theta = NEG_INF;
    #pragma unroll 1
    for (int p = 0; p < KTH; ++p) {
        float h = s[3];
        float m = h;
        m = fmaxf(m, __shfl_xor(m, 1));
        m = fmaxf(m, __shfl_xor(m, 2));
        m = fmaxf(m, __shfl_xor(m, 4));
        m = fmaxf(m, __shfl_xor(m, 8));
        unsigned long long bal = __ballot(h == m);
        unsigned qb = (unsigned)((bal >> (lane & 48)) & 0xFFFFull);
        int owner = __ffs(qb) - 1;
        if ((lane & 15) == owner) {
            s[3] = s[2]; s[2] = s[1]; s[1] = s[0]; s[0] = NEG_INF;
        }
        theta = m;
    }
    return theta;
}

// exact sorted-9 insert, value desc w/ index-asc tiebreak (final sort only)
__device__ __forceinline__ void insert9x(float w, int wi, float (&s)[9], int (&si)[9]) {
    bool c[9];
    #pragma unroll
    for (int k = 0; k < 9; ++k) c[k] = (w > s[k]) || (w == s[k] && wi < si[k]);
    #pragma unroll
    for (int k = 0; k < 8; ++k) si[k] = c[k + 1] ? si[k + 1] : (c[k] ? wi : si[k]);
    si[8] = c[8] ? wi : si[8];
    #pragma unroll
    for (int k = 0; k < 8; ++k) s[k] = c[k + 1] ? s[k + 1] : (c[k] ? w : s[k]);
    s[8] = c[8] ? w : s[8];
}

// ---------------------------------------------------------------------------
// K0: repack conv_w[o][cc*9+kk] -> cwp[kk][cc][o]
// ---------------------------------------------------------------------------
__global__ void repack_cw_kernel(const float* __restrict__ cw, float* __restrict__ cwp) {
    int e = blockIdx.x * blockDim.x + threadIdx.x;
    if (e >= KNN * CH * CH) return;
    int o  = e & 63;
    int cc = (e >> 6) & 63;
    int kk = e >> 12;
    cwp[e] = cw[o * (CH * KNN) + cc * KNN + kk];
}

// ---------------------------------------------------------------------------
// K1: QKV + L2 normalize + u-projection (u bf16) + q/k T-layout fp32 & bf16.
//     q bf16 is written in MFMA B-FRAGMENT ORDER (round-9 change):
//       frag[b][j0][ks][lane]*8, lane = quad*16+l15 holds
//       q[col=j0*16+l15][k=ks*32+quad*8 .. +8]
//     so each sim_topk q load is lane-contiguous 1KB (1 transaction) instead
//     of 16 scattered 64B segments (the r8-probe-measured 104 µs cost).
// ---------------------------------------------------------------------------
__global__ __launch_bounds__(256) void qkvu_kernel(
        const float* __restrict__ x,
        const float* __restrict__ Wq, const float* __restrict__ Wk, const float* __restrict__ Wv,
        const float* __restrict__ cwp,
        float* __restrict__ qtf, float* __restrict__ ktf,
        unsigned short* __restrict__ qtb, unsigned short* __restrict__ ktb,
        unsigned short* __restrict__ ub) {
    __shared__ __align__(16) float xs[CH * 64];
    __shared__ __align__(16) float vs[CH * 64];
    __shared__ __align__(16) float wl[CH * 64];
    __shared__ float pq[4 * 64], pk[4 * 64];

    const int b   = blockIdx.x >> 6;
    const int tb  = blockIdx.x & 63;
    const int tid = threadIdx.x;

    const float* xb = x + ((size_t)b * CH) * TT + tb * 64;
    #pragma unroll
    for (int m = 0; m < 16; ++m) {
        int l = tid + 256 * m;
        xs[l] = xb[(size_t)(l >> 6) * TT + (l & 63)];
    }
    __syncthreads();

    const int t = tid & 63;
    const int g = __builtin_amdgcn_readfirstlane(tid >> 6);
    const int d0 = g * 16;

    float qa[16], ka[16], va[16];
    #pragma unroll
    for (int dd = 0; dd < 16; ++dd) { qa[dd] = 0.f; ka[dd] = 0.f; va[dd] = 0.f; }

    #pragma unroll 4
    for (int c = 0; c < CH; ++c) {
        float xv = xs[c * 64 + t];
        #pragma unroll
        for (int dd = 0; dd < 16; ++dd) {
            qa[dd] = fmaf(Wq[(d0 + dd) * CH + c], xv, qa[dd]);
            ka[dd] = fmaf(Wk[(d0 + dd) * CH + c], xv, ka[dd]);
            va[dd] = fmaf(Wv[(d0 + dd) * CH + c], xv, va[dd]);
        }
    }

    float sq = 0.f, sk = 0.f;
    #pragma unroll
    for (int dd = 0; dd < 16; ++dd) { sq = fmaf(qa[dd], qa[dd], sq); sk = fmaf(ka[dd], ka[dd], sk); }
    pq[g * 64 + t] = sq;
    pk[g * 64 + t] = sk;
    __syncthreads();

    const float nq = sqrtf(pq[t] + pq[64 + t] + pq[128 + t] + pq[192 + t]);
    const float nk = sqrtf(pk[t] + pk[64 + t] + pk[128 + t] + pk[192 + t]);
    const float isq = 1.0f / fmaxf(nq, 1e-12f);
    const float isk = 1.0f / fmaxf(nk, 1e-12f);

    const size_t tg = (size_t)tb * 64 + t;
    float qn[16], kn[16];
    #pragma unroll
    for (int dd = 0; dd < 16; ++dd) {
        qn[dd] = qa[dd] * isq;
        kn[dd] = ka[dd] * isk;
        vs[(d0 + dd) * 64 + t] = va[dd];
    }
    float* qf = qtf + ((size_t)b * TT + tg) * CH + d0;
    float* kf = ktf + ((size_t)b * TT + tg) * CH + d0;
    #pragma unroll
    for (int p = 0; p < 4; ++p) {
        *(float4*)&qf[p * 4] = make_float4(qn[p*4], qn[p*4+1], qn[p*4+2], qn[p*4+3]);
        *(float4*)&kf[p * 4] = make_float4(kn[p*4], kn[p*4+1], kn[p*4+2], kn[p*4+3]);
    }
    // k bf16: row-major (A-fragments are only 4 loads/kernel in sim)
    unsigned* kh = (unsigned*)(ktb + ((size_t)b * TT + tg) * CH + d0);
    #pragma unroll
    for (int p = 0; p < 8; ++p)
        kh[p] = (unsigned)f2bf(kn[2*p]) | ((unsigned)f2bf(kn[2*p+1]) << 16);

    // q bf16: FRAGMENT order. Thread (g, col tg) owns k = g*16..+15 =
    // chunks (ks=g>>1, quad=(g&1)*2+h), h=0,1. Each chunk: 8 bf16 = 16B at
    // offset (((b*256 + j0)*2 + ks)*64 + (quad*16 + l15)) * 8 ushorts.
    {
        const int j0   = (int)(tg >> 4);
        const int l15q = (int)tg & 15;
        const int ks   = g >> 1;
        const int q0   = (g & 1) * 2;
        #pragma unroll
        for (int h = 0; h < 2; ++h) {
            unsigned w0 = (unsigned)f2bf(qn[h*8+0]) | ((unsigned)f2bf(qn[h*8+1]) << 16);
            unsigned w1 = (unsigned)f2bf(qn[h*8+2]) | ((unsigned)f2bf(qn[h*8+3]) << 16);
            unsigned w2 = (unsigned)f2bf(qn[h*8+4]) | ((unsigned)f2bf(qn[h*8+5]) << 16);
            unsigned w3 = (unsigned)f2bf(qn[h*8+6]) | ((unsigned)f2bf(qn[h*8+7]) << 16);
            unsigned short* dst = qtb +
                ((((size_t)b * 256 + j0) * 2 + ks) * 64 + ((q0 + h) * 16 + l15q)) * 8;
            *(uint4*)dst = make_uint4(w0, w1, w2, w3);
        }
    }
    __syncthreads();

    const int to = tid & 15;
    const int tt = tid >> 4;
    for (int kk = 0; kk < KNN; ++kk) {
        #pragma unroll
        for (int m = 0; m < 16; ++m) {
            int l = tid + 256 * m;
            wl[l] = cwp[kk * (CH * CH) + l];
        }
        __syncthreads();
        float acc[4][4];
        #pragma unroll
        for (int i = 0; i < 4; ++i)
            #pragma unroll
            for (int j = 0; j < 4; ++j) acc[i][j] = 0.f;

        #pragma unroll 8
        for (int cc = 0; cc < CH; ++cc) {
            float4 wv = *(const float4*)&wl[cc * 64 + 4 * to];
            float4 vv = *(const float4*)&vs[cc * 64 + 4 * tt];
            const float wj[4] = {wv.x, wv.y, wv.z, wv.w};
            const float vi[4] = {vv.x, vv.y, vv.z, vv.w};
            #pragma unroll
            for (int i = 0; i < 4; ++i)
                #pragma unroll
                for (int j = 0; j < 4; ++j) acc[i][j] = fmaf(vi[i], wj[j], acc[i][j]);
        }
        #pragma unroll
        for (int i = 0; i < 4; ++i) {
            size_t row = (size_t)(b * KNN + kk) * TT + tb * 64 + 4 * tt + i;
            unsigned w0 = (unsigned)f2bf(acc[i][0]) | ((unsigned)f2bf(acc[i][1]) << 16);
            unsigned w1 = (unsigned)f2bf(acc[i][2]) | ((unsigned)f2bf(acc[i][3]) << 16);
            *(uint2*)&ub[row * CH + 4 * to] = make_uint2(w0, w1);
        }
        __syncthreads();
    }
}

// ---------------------------------------------------------------------------
// K2: BARRIER-FREE bf16-MFMA sim + top-4 prefilter + θ-collect + exact rescore
//     r0 structure; round-9 change: q loads hit the FRAGMENT-ORDER buffer —
//     each load = base + lane*16B, contiguous 1KB/instruction (was 16
//     scattered 64B segments = the probe-measured 104 µs TA cost).
// ---------------------------------------------------------------------------
__global__ __launch_bounds__(256, 2) void sim_topk_kernel(
        const unsigned short* __restrict__ qtb, const unsigned short* __restrict__ ktb,
        const float* __restrict__ qtf, const float* __restrict__ ktf,
        int* __restrict__ idxout) {
    __shared__ int   cnt[64];
    __shared__ int   bkt[64 * SLOTS];
    __shared__ float wbf[64 * SLOTS];

    const int b    = blockIdx.x & 7;
    const int ib   = blockIdx.x >> 3;      // 0..63
    const int tid  = threadIdx.x;
    const int lane = tid & 63;
    const int w    = tid >> 6;             // wave 0..3
    const int w2r  = w >> 1;               // row half
    const int w2c  = w & 1;                // col half
    const int quad = lane >> 4;
    const int l15  = lane & 15;

    if (tid < 64) cnt[tid] = 0;
    __syncthreads();

    // k A-fragments in registers: rows w2r*32 + rt*16 + l15, k = quad*8+ks*32
    const unsigned short* kb = ktb + ((size_t)b * TT + ib * 64 + w2r * 32) * CH;
    s16x8 ka[2][2];
    #pragma unroll
    for (int rt = 0; rt < 2; ++rt)
        #pragma unroll
        for (int ks = 0; ks < 2; ++ks)
            ka[rt][ks] = *(const s16x8*)(kb + (size_t)(rt * 16 + l15) * CH + ks * 32 + quad * 8);

    // fragment-order q base for this batch & col-half:
    // frag[(b*256 + j0)*2 + ks][lane]*8, j0 = w2c*128 + jt*8 + jj
    const unsigned short* qfb = qtb + (((size_t)b * 256 + (size_t)w2c * 128) * 2) * 512
                                + (size_t)lane * 8;

    float s[2][4][4];
    #pragma unroll
    for (int rt = 0; rt < 2; ++rt)
        #pragma unroll
        for (int rg = 0; rg < 4; ++rg)
            #pragma unroll
            for (int k = 0; k < 4; ++k) s[rt][rg][k] = NEG_INF;

    // ------------------ PASS A: values-only top-4 (no barriers) ------------
    for (int jt = 0; jt < 16; ++jt) {
        const unsigned short* qrow = qfb + (size_t)(jt * 8) * 1024;  // j0 step=2*512
        s16x8 qf[8][2];
        #pragma unroll
        for (int jj = 0; jj < 8; ++jj)
            #pragma unroll
            for (int ks = 0; ks < 2; ++ks)
                qf[jj][ks] = *(const s16x8*)(qrow + (size_t)(jj * 2 + ks) * 512);

        f32x4 acc[2][8];
        #pragma unroll
        for (int rt = 0; rt < 2; ++rt)
            #pragma unroll
            for (int jj = 0; jj < 8; ++jj) acc[rt][jj] = (f32x4){0.f, 0.f, 0.f, 0.f};
        #pragma unroll
        for (int ks = 0; ks < 2; ++ks)
            #pragma unroll
            for (int rt = 0; rt < 2; ++rt)
                #pragma unroll
                for (int jj = 0; jj < 8; ++jj)
                    acc[rt][jj] = __builtin_amdgcn_mfma_f32_16x16x32_bf16(ka[rt][ks], qf[jj][ks], acc[rt][jj], 0, 0, 0);

        #pragma unroll
        for (int rt = 0; rt < 2; ++rt)
            #pragma unroll
            for (int jj = 0; jj < 8; ++jj) {
                insert4(acc[rt][jj][0], s[rt][0]);
                insert4(acc[rt][jj][1], s[rt][1]);
                insert4(acc[rt][jj][2], s[rt][2]);
                insert4(acc[rt][jj][3], s[rt][3]);
            }
    }

    // per-(row,half) θ — valid per half; no cross-wave merge needed
    float th[2][4];
    #pragma unroll
    for (int rt = 0; rt < 2; ++rt) {
        th[rt][0] = popTheta4(s[rt][0], lane);
        th[rt][1] = popTheta4(s[rt][1], lane);
        th[rt][2] = popTheta4(s[rt][2], lane);
        th[rt][3] = popTheta4(s[rt][3], lane);
    }

    // ------------------ PASS B: recompute (bitwise-identical) + collect ----
    for (int jt = 0; jt < 16; ++jt) {
        const unsigned short* qrow = qfb + (size_t)(jt * 8) * 1024;
        s16x8 qf[8][2];
        #pragma unroll
        for (int jj = 0; jj < 8; ++jj)
            #pragma unroll
            for (int ks = 0; ks < 2; ++ks)
                qf[jj][ks] = *(const s16x8*)(qrow + (size_t)(jj * 2 + ks) * 512);

        f32x4 acc[2][8];
        #pragma unroll
        for (int rt = 0; rt < 2; ++rt)
            #pragma unroll
            for (int jj = 0; jj < 8; ++jj) acc[rt][jj] = (f32x4){0.f, 0.f, 0.f, 0.f};
        #pragma unroll
        for (int ks = 0; ks < 2; ++ks)
            #pragma unroll
            for (int rt = 0; rt < 2; ++rt)
                #pragma unroll
                for (int jj = 0; jj < 8; ++jj)
                    acc[rt][jj] = __builtin_amdgcn_mfma_f32_16x16x32_bf16(ka[rt][ks], qf[jj][ks], acc[rt][jj], 0, 0, 0);

        #pragma unroll
        for (int rt = 0; rt < 2; ++rt)
            #pragma unroll
            for (int jj = 0; jj < 8; ++jj) {
                const int j = w2c * 2048 + jt * 128 + jj * 16 + l15;
                #pragma unroll
                for (int rg = 0; rg < 4; ++rg) {
                    if (acc[rt][jj][rg] >= th[rt][rg]) {
                        int rowl = w2r * 32 + rt * 16 + quad * 4 + rg;
                        int sl = atomicAdd(&cnt[rowl], 1);
                        if (sl < SLOTS) bkt[rowl * SLOTS + sl] = j;
                    }
                }
            }
    }
    __syncthreads();

    // ------------------ exact fp32 rescore (L2-hot q/k fp32) ---------------
    {
        int r = tid >> 2, sub = tid & 3;
        int n = min(cnt[r], SLOTS);
        const float* krow = ktf + ((size_t)b * TT + ib * 64 + r) * CH;
        for (int m = sub; m < n; m += 4) {
            int j = bkt[r * SLOTS + m];
            const float* qrow = qtf + ((size_t)b * TT + j) * CH;
            float wv = 0.f;
            #pragma unroll
            for (int c4 = 0; c4 < 16; ++c4) {
                float4 kv = *(const float4*)&krow[c4 * 4];
                float4 qv = *(const float4*)&qrow[c4 * 4];
                wv = fmaf(kv.x, qv.x, wv); wv = fmaf(kv.y, qv.y, wv);
                wv = fmaf(kv.z, qv.z, wv); wv = fmaf(kv.w, qv.w, wv);
            }
            wbf[r * SLOTS + m] = wv;
        }
    }
    __syncthreads();

    if (tid < 64) {
        int n = min(cnt[tid], SLOTS);
        float s9[9]; int si9[9];
        #pragma unroll
        for (int k = 0; k < 9; ++k) { s9[k] = NEG_INF; si9[k] = 0x7fffffff; }
        #pragma unroll 1
        for (int m = 0; m < n; ++m) insert9x(wbf[tid * SLOTS + m], bkt[tid * SLOTS + m], s9, si9);
        int* orow = idxout + ((size_t)b * TT + ib * 64 + tid) * KNN;
        #pragma unroll
        for (int m = 0; m < 9; ++m) orow[m] = si9[8 - m];
    }
}

// ---------------------------------------------------------------------------
// K3: out[b][o][t] = conv_b[o] + sum_kk u_bf16[b][kk][idx[t][kk]][o]
// ---------------------------------------------------------------------------
__global__ __launch_bounds__(256) void gather_conv_kernel(
        const unsigned short* __restrict__ ub, const int* __restrict__ idxin,
        const float* __restrict__ conv_b, float* __restrict__ out) {
    __shared__ int   sidx[64 * KNN];
    __shared__ float cb[CH];
    const int b   = blockIdx.x & 7;
    const int tb  = blockIdx.x >> 3;
    const int tid = threadIdx.x;

    if (tid < CH) cb[tid] = conv_b[tid];
    const int* ig = idxin + ((size_t)b * TT + tb * 64) * KNN;
    for (int l = tid; l < 64 * KNN; l += 256) sidx[l] = ig[l];
    __syncthreads();

    const int tl = tid & 63;
    const int og = tid >> 6;
    const int o0 = og * 16;

    float acc[16];
    #pragma unroll
    for (int q = 0; q < 16; ++q) acc[q] = cb[o0 + q];

    #pragma unroll
    for (int kk = 0; kk < KNN; ++kk) {
        int j = sidx[tl * KNN + kk];
        const unsigned short* up = ub + (((size_t)(b * KNN + kk)) * TT + j) * CH + o0;
        #pragma unroll
        for (int q8 = 0; q8 < 2; ++q8) {
            uint4 raw = *(const uint4*)&up[q8 * 8];
            unsigned rw[4] = {raw.x, raw.y, raw.z, raw.w};
            #pragma unroll
            for (int p = 0; p < 4; ++p) {
                acc[q8 * 8 + 2 * p]     += __uint_as_float(rw[p] << 16);
                acc[q8 * 8 + 2 * p + 1] += __uint_as_float(rw[p] & 0xFFFF0000u);
            }
        }
    }
    const int t = tb * 64 + tl;
    #pragma unroll
    for (int q = 0; q < 16; ++q)
        out[((size_t)b * CH + o0 + q) * TT + t] = acc[q];
}

// ---------------------------------------------------------------------------
extern "C" void kernel_launch(void* const* d_in, const int* in_sizes, int n_in,
                              void* d_out, int out_size, void* d_ws, size_t ws_size,
                              hipStream_t stream) {
    const float* x   = (const float*)d_in[0];
    const float* Wq  = (const float*)d_in[1];
    const float* Wk  = (const float*)d_in[2];
    const float* Wv  = (const float*)d_in[3];
    const float* cw  = (const float*)d_in[4];
    const float* cbp = (const float*)d_in[5];

    float* ws = (float*)d_ws;
    unsigned short* ub  = (unsigned short*)(ws + OFF_UB);
    float* qtf          = ws + OFF_QTF;
    float* ktf          = ws + OFF_KTF;
    unsigned short* qtb = (unsigned short*)(ws + OFF_QTB);
    unsigned short* ktb = (unsigned short*)(ws + OFF_KTB);
    int*   idx          = (int*)(ws + OFF_IDX);
    float* cwp          = ws + OFF_CWP;
    float* out          = (float*)d_out;

    repack_cw_kernel<<<(KNN * CH * CH + 255) / 256, 256, 0, stream>>>(cw, cwp);
    qkvu_kernel<<<BB * 64, 256, 0, stream>>>(x, Wq, Wk, Wv, cwp, qtf, ktf, qtb, ktb, ub);
    sim_topk_kernel<<<BB * 64, 256, 0, stream>>>(qtb, ktb, qtf, ktf, idx);
    gather_conv_kernel<<<BB * 64, 256, 0, stream>>>(ub, idx, cbp, out);
}